// Round 1
// baseline (180.019 us; speedup 1.0000x reference)
//
#include <hip/hip_runtime.h>
#include <stdint.h>

// ---------------------------------------------------------------------------
// RDFBins: species-pair radial distribution histogram.
//   out[si, sj, b] = #(pairs with species(first)=si, species(second)=sj,
//                      bins[b] <= d < bins[b+1]) / n_molecules
// Inputs (d_in order): pair_dist f32[NP], pair_first i32[NP], pair_second
// i32[NP], one_hot bool[NA,4], n_molecules i32[1], bins f32[NE].
// ---------------------------------------------------------------------------

#define NSPEC 4

// Element size of the one-hot buffer, inferred from the count of nonzero
// bytes in its first n_atoms*NSPEC bytes (strict one-hot rows):
//   u8  -> n_atoms nonzero bytes
//   f32 -> n_atoms/2   (two nonzero bytes per 1.0f, quarter of rows seen)
//   i32 -> n_atoms/4
//   i64 -> n_atoms/8
__device__ inline int esize_from_nz(unsigned int nz, int n_atoms) {
    if (nz >= (unsigned)(n_atoms - n_atoms / 4)) return 1;  // >= 3/4 n
    if (nz >= (unsigned)((n_atoms * 3) / 16)) return 4;     // covers n/2, n/4
    return 8;
}

__device__ inline int get_species(const uint8_t* oh, int atom, int E) {
    if (E == 1) {
        uint32_t v = *(const uint32_t*)(oh + (size_t)atom * 4);
        if (v & 0x000000FFu) return 0;
        if (v & 0x0000FF00u) return 1;
        if (v & 0x00FF0000u) return 2;
        return 3;
    }
    const uint8_t* p = oh + (size_t)atom * 4 * E;
    for (int s = 0; s < NSPEC; ++s) {
        bool nzb = false;
        for (int b = 0; b < E; ++b) nzb |= (p[s * E + b] != 0);
        if (nzb) return s;
    }
    return 0;
}

// --- kernel 1: count nonzero bytes in first nbytes of one_hot --------------
__global__ void k_detect(const uint8_t* __restrict__ oh, int nbytes,
                         unsigned int* __restrict__ nz_out) {
    int tid = blockIdx.x * blockDim.x + threadIdx.x;
    int stride = gridDim.x * blockDim.x;
    const uint32_t* w = (const uint32_t*)oh;
    int nw = nbytes >> 2;
    unsigned int local = 0;
    for (int i = tid; i < nw; i += stride) {
        uint32_t v = w[i];
        local += (v & 0x000000FFu) != 0;
        local += (v & 0x0000FF00u) != 0;
        local += (v & 0x00FF0000u) != 0;
        local += (v & 0xFF000000u) != 0;
    }
    for (int off = 32; off > 0; off >>= 1) local += __shfl_down(local, off);
    __shared__ unsigned int wsum[16];
    int lane = threadIdx.x & 63, wv = threadIdx.x >> 6;
    if (lane == 0) wsum[wv] = local;
    __syncthreads();
    if (threadIdx.x == 0) {
        unsigned int s = 0;
        int nwaves = (blockDim.x + 63) >> 6;
        for (int i = 0; i < nwaves; ++i) s += wsum[i];
        atomicAdd(nz_out, s);
    }
}

// --- kernel 2: species label per atom --------------------------------------
__global__ void k_species(const uint8_t* __restrict__ oh, int n_atoms,
                          const unsigned int* __restrict__ nz,
                          uint8_t* __restrict__ sp) {
    int E = esize_from_nz(*nz, n_atoms);
    int tid = blockIdx.x * blockDim.x + threadIdx.x;
    int stride = gridDim.x * blockDim.x;
    for (int i = tid; i < n_atoms; i += stride)
        sp[i] = (uint8_t)get_species(oh, i, E);
}

// --- kernel 3: histogram ----------------------------------------------------
template <bool TABLE>
__global__ void k_hist(const float* __restrict__ dist,
                       const int* __restrict__ pf, const int* __restrict__ ps,
                       const uint8_t* __restrict__ sp,
                       const uint8_t* __restrict__ oh,
                       const unsigned int* __restrict__ nz, int n_atoms,
                       const float* __restrict__ bins, int n_edges, int npairs,
                       unsigned int* __restrict__ counts) {
    const int n_bins = n_edges - 1;
    const int nh = NSPEC * NSPEC * n_bins;
    extern __shared__ float smem[];
    float* sb = smem;              // n_edges floats
    int* h = (int*)(smem + n_edges);
    const int tid = threadIdx.x;
    for (int j = tid; j < n_edges; j += blockDim.x) sb[j] = bins[j];
    for (int j = tid; j < nh; j += blockDim.x) h[j] = 0;
    __syncthreads();

    int E = 1;
    if (!TABLE) E = esize_from_nz(*nz, n_atoms);
    const float lo = sb[0];
    const float hi = sb[n_edges - 1];
    const float scale = (float)n_bins / (hi - lo);

    const int gid = blockIdx.x * blockDim.x + tid;
    const int gsz = gridDim.x * blockDim.x;

    auto process = [&](float d, int a0, int a1) {
        if (d >= lo && d < hi) {
            int b = (int)((d - lo) * scale);
            b = b < n_bins - 1 ? b : n_bins - 1;
            // exact fix-up against real edges (== searchsorted(right)-1)
            while (d < sb[b]) --b;
            while (d >= sb[b + 1]) ++b;
            int si, sj;
            if (TABLE) {
                si = sp[a0];
                sj = sp[a1];
            } else {
                si = get_species(oh, a0, E);
                sj = get_species(oh, a1, E);
            }
            atomicAdd(&h[(si * NSPEC + sj) * n_bins + b], 1);
        }
    };

    const int nquads = npairs >> 2;
    for (int q = gid; q < nquads; q += gsz) {
        float4 d4 = ((const float4*)dist)[q];
        int4 f4 = ((const int4*)pf)[q];
        int4 s4 = ((const int4*)ps)[q];
        process(d4.x, f4.x, s4.x);
        process(d4.y, f4.y, s4.y);
        process(d4.z, f4.z, s4.z);
        process(d4.w, f4.w, s4.w);
    }
    int tail = npairs & 3;
    if (gid < tail) {
        int i = (nquads << 2) + gid;
        process(dist[i], pf[i], ps[i]);
    }

    __syncthreads();
    for (int j = tid; j < nh; j += blockDim.x) {
        int v = h[j];
        if (v) atomicAdd(&counts[j], (unsigned int)v);
    }
}

// --- kernel 4: normalize ----------------------------------------------------
__global__ void k_final(const unsigned int* __restrict__ counts,
                        const int* __restrict__ nmol, float* __restrict__ out,
                        int n) {
    int i = blockIdx.x * blockDim.x + threadIdx.x;
    if (i < n) out[i] = (float)counts[i] / (float)(*nmol);
}

extern "C" void kernel_launch(void* const* d_in, const int* in_sizes, int n_in,
                              void* d_out, int out_size, void* d_ws,
                              size_t ws_size, hipStream_t stream) {
    const float* dist = (const float*)d_in[0];
    const int* pf = (const int*)d_in[1];
    const int* ps = (const int*)d_in[2];
    const uint8_t* oh = (const uint8_t*)d_in[3];
    const int* nmol = (const int*)d_in[4];
    const float* bins = (const float*)d_in[5];
    float* out = (float*)d_out;

    const int npairs = in_sizes[0];
    const int n_edges = in_sizes[5];
    const int n_bins = n_edges - 1;
    const int n_atoms = in_sizes[3] / NSPEC;
    const int nh = NSPEC * NSPEC * n_bins;  // 1600

    uint8_t* ws = (uint8_t*)d_ws;
    unsigned int* counts = (unsigned int*)ws;           // nh u32
    unsigned int* nz = (unsigned int*)(ws + nh * 4);    // 1 u32
    uint8_t* sp = ws + nh * 4 + 4;                      // n_atoms u8
    const size_t need_table = (size_t)nh * 4 + 4 + (size_t)n_atoms;
    const bool use_table = ws_size >= need_table;

    hipMemsetAsync(d_ws, 0, nh * 4 + 4, stream);

    k_detect<<<512, 256, 0, stream>>>(oh, n_atoms * NSPEC, nz);

    if (use_table)
        k_species<<<(n_atoms + 255) / 256, 256, 0, stream>>>(oh, n_atoms, nz,
                                                             sp);

    const size_t shmem = (size_t)n_edges * 4 + (size_t)nh * 4;
    const int blocks = 1024;
    if (use_table)
        k_hist<true><<<blocks, 256, shmem, stream>>>(
            dist, pf, ps, sp, oh, nz, n_atoms, bins, n_edges, npairs, counts);
    else
        k_hist<false><<<blocks, 256, shmem, stream>>>(
            dist, pf, ps, sp, oh, nz, n_atoms, bins, n_edges, npairs, counts);

    k_final<<<(out_size + 255) / 256, 256, 0, stream>>>(counts, nmol, out,
                                                        out_size);
}

// Round 2
// 162.821 us; speedup vs baseline: 1.1056x; 1.1056x over previous
//
#include <hip/hip_runtime.h>
#include <stdint.h>

// ---------------------------------------------------------------------------
// RDFBins: species-pair radial distribution histogram.
//   out[si, sj, b] = #(pairs with species(first)=si, species(second)=sj,
//                      bins[b] <= d < bins[b+1]) / n_molecules
// Inputs (d_in order): pair_dist f32[NP], pair_first i32[NP], pair_second
// i32[NP], one_hot bool[NA,4], n_molecules i32[1], bins f32[NE].
//
// R2: latency-bound fix — 2-bit packed species table (50 KB, L1/L2-resident),
// 2048 blocks for 100% occupancy, 2-quad ILP batching of the random gathers.
// ---------------------------------------------------------------------------

#define NSPEC 4

// Element size of the one-hot buffer, inferred from the count of nonzero
// bytes in its first n_atoms*NSPEC bytes (strict one-hot rows):
//   u8 -> n_atoms, f32 -> n_atoms/2, i32 -> n_atoms/4, i64 -> n_atoms/8
__device__ inline int esize_from_nz(unsigned int nz, int n_atoms) {
    if (nz >= (unsigned)(n_atoms - n_atoms / 4)) return 1;  // >= 3/4 n
    if (nz >= (unsigned)((n_atoms * 3) / 16)) return 4;     // covers n/2, n/4
    return 8;
}

__device__ inline int get_species(const uint8_t* oh, int atom, int E) {
    if (E == 1) {
        uint32_t v = *(const uint32_t*)(oh + (size_t)atom * 4);
        if (v & 0x000000FFu) return 0;
        if (v & 0x0000FF00u) return 1;
        if (v & 0x00FF0000u) return 2;
        return 3;
    }
    const uint8_t* p = oh + (size_t)atom * 4 * E;
    for (int s = 0; s < NSPEC; ++s) {
        bool nzb = false;
        for (int b = 0; b < E; ++b) nzb |= (p[s * E + b] != 0);
        if (nzb) return s;
    }
    return 0;
}

// --- kernel 1: count nonzero bytes in first nbytes of one_hot --------------
__global__ void k_detect(const uint8_t* __restrict__ oh, int nbytes,
                         unsigned int* __restrict__ nz_out) {
    int tid = blockIdx.x * blockDim.x + threadIdx.x;
    int stride = gridDim.x * blockDim.x;
    const uint32_t* w = (const uint32_t*)oh;
    int nw = nbytes >> 2;
    unsigned int local = 0;
    for (int i = tid; i < nw; i += stride) {
        uint32_t v = w[i];
        local += (v & 0x000000FFu) != 0;
        local += (v & 0x0000FF00u) != 0;
        local += (v & 0x00FF0000u) != 0;
        local += (v & 0xFF000000u) != 0;
    }
    for (int off = 32; off > 0; off >>= 1) local += __shfl_down(local, off);
    __shared__ unsigned int wsum[16];
    int lane = threadIdx.x & 63, wv = threadIdx.x >> 6;
    if (lane == 0) wsum[wv] = local;
    __syncthreads();
    if (threadIdx.x == 0) {
        unsigned int s = 0;
        int nwaves = (blockDim.x + 63) >> 6;
        for (int i = 0; i < nwaves; ++i) s += wsum[i];
        atomicAdd(nz_out, s);
    }
}

// --- kernel 2: species labels packed 2 bits/atom ---------------------------
__global__ void k_species(const uint8_t* __restrict__ oh, int n_atoms,
                          const unsigned int* __restrict__ nz,
                          uint32_t* __restrict__ sp2) {
    int E = esize_from_nz(*nz, n_atoms);
    int tid = blockIdx.x * blockDim.x + threadIdx.x;
    int stride = gridDim.x * blockDim.x;
    int nw = (n_atoms + 15) >> 4;
    for (int w = tid; w < nw; w += stride) {
        uint32_t word = 0;
        int base = w << 4;
        int lim = n_atoms - base;
        lim = lim < 16 ? lim : 16;
        for (int k = 0; k < lim; ++k)
            word |= (uint32_t)get_species(oh, base + k, E) << (k * 2);
        sp2[w] = word;
    }
}

// --- kernel 3: histogram ----------------------------------------------------
template <bool TABLE>
__launch_bounds__(256, 8) __global__
void k_hist(const float* __restrict__ dist, const int* __restrict__ pf,
            const int* __restrict__ ps, const uint32_t* __restrict__ sp2,
            const uint8_t* __restrict__ oh,
            const unsigned int* __restrict__ nz, int n_atoms,
            const float* __restrict__ bins, int n_edges, int npairs,
            unsigned int* __restrict__ counts) {
    const int n_bins = n_edges - 1;
    const int nh = NSPEC * NSPEC * n_bins;
    extern __shared__ float smem[];
    float* sb = smem;              // n_edges floats
    int* h = (int*)(smem + n_edges);
    const int tid = threadIdx.x;
    for (int j = tid; j < n_edges; j += blockDim.x) sb[j] = bins[j];
    for (int j = tid; j < nh; j += blockDim.x) h[j] = 0;
    __syncthreads();

    int E = 1;
    if (!TABLE) E = esize_from_nz(*nz, n_atoms);
    const float lo = sb[0];
    const float hi = sb[n_edges - 1];
    const float scale = (float)n_bins / (hi - lo);

    const int gid = blockIdx.x * blockDim.x + tid;
    const int gsz = gridDim.x * blockDim.x;

    auto species_of = [&](int a) -> int {
        if (TABLE) return (int)((sp2[a >> 4] >> ((a & 15) << 1)) & 3u);
        return get_species(oh, a, E);
    };

    auto bin_and_add = [&](float d, int si, int sj) {
        if (d >= lo && d < hi) {
            int b = (int)((d - lo) * scale);
            b = b < n_bins - 1 ? b : n_bins - 1;
            // exact fix-up against real edges (== searchsorted(right)-1)
            while (d < sb[b]) --b;
            while (d >= sb[b + 1]) ++b;
            atomicAdd(&h[(si * NSPEC + sj) * n_bins + b], 1);
        }
    };

    const int nquads = npairs >> 2;
    int q = gid;
    // main loop: 2 quads (8 pairs) per iteration; all 16 gathers staged first
    for (; q + gsz < nquads; q += 2 * gsz) {
        const int qa = q, qb = q + gsz;
        float4 dA = ((const float4*)dist)[qa];
        int4 fA = ((const int4*)pf)[qa];
        int4 sA = ((const int4*)ps)[qa];
        float4 dB = ((const float4*)dist)[qb];
        int4 fB = ((const int4*)pf)[qb];
        int4 sB = ((const int4*)ps)[qb];
        int si0 = species_of(fA.x), sj0 = species_of(sA.x);
        int si1 = species_of(fA.y), sj1 = species_of(sA.y);
        int si2 = species_of(fA.z), sj2 = species_of(sA.z);
        int si3 = species_of(fA.w), sj3 = species_of(sA.w);
        int si4 = species_of(fB.x), sj4 = species_of(sB.x);
        int si5 = species_of(fB.y), sj5 = species_of(sB.y);
        int si6 = species_of(fB.z), sj6 = species_of(sB.z);
        int si7 = species_of(fB.w), sj7 = species_of(sB.w);
        bin_and_add(dA.x, si0, sj0);
        bin_and_add(dA.y, si1, sj1);
        bin_and_add(dA.z, si2, sj2);
        bin_and_add(dA.w, si3, sj3);
        bin_and_add(dB.x, si4, sj4);
        bin_and_add(dB.y, si5, sj5);
        bin_and_add(dB.z, si6, sj6);
        bin_and_add(dB.w, si7, sj7);
    }
    if (q < nquads) {
        float4 d4 = ((const float4*)dist)[q];
        int4 f4 = ((const int4*)pf)[q];
        int4 s4 = ((const int4*)ps)[q];
        bin_and_add(d4.x, species_of(f4.x), species_of(s4.x));
        bin_and_add(d4.y, species_of(f4.y), species_of(s4.y));
        bin_and_add(d4.z, species_of(f4.z), species_of(s4.z));
        bin_and_add(d4.w, species_of(f4.w), species_of(s4.w));
    }
    int tail = npairs & 3;
    if (gid < tail) {
        int i = (nquads << 2) + gid;
        bin_and_add(dist[i], species_of(pf[i]), species_of(ps[i]));
    }

    __syncthreads();
    for (int j = tid; j < nh; j += blockDim.x) {
        int v = h[j];
        if (v) atomicAdd(&counts[j], (unsigned int)v);
    }
}

// --- kernel 4: normalize ----------------------------------------------------
__global__ void k_final(const unsigned int* __restrict__ counts,
                        const int* __restrict__ nmol, float* __restrict__ out,
                        int n) {
    int i = blockIdx.x * blockDim.x + threadIdx.x;
    if (i < n) out[i] = (float)counts[i] / (float)(*nmol);
}

extern "C" void kernel_launch(void* const* d_in, const int* in_sizes, int n_in,
                              void* d_out, int out_size, void* d_ws,
                              size_t ws_size, hipStream_t stream) {
    const float* dist = (const float*)d_in[0];
    const int* pf = (const int*)d_in[1];
    const int* ps = (const int*)d_in[2];
    const uint8_t* oh = (const uint8_t*)d_in[3];
    const int* nmol = (const int*)d_in[4];
    const float* bins = (const float*)d_in[5];
    float* out = (float*)d_out;

    const int npairs = in_sizes[0];
    const int n_edges = in_sizes[5];
    const int n_bins = n_edges - 1;
    const int n_atoms = in_sizes[3] / NSPEC;
    const int nh = NSPEC * NSPEC * n_bins;  // 1600

    uint8_t* ws = (uint8_t*)d_ws;
    unsigned int* counts = (unsigned int*)ws;            // nh u32
    unsigned int* nz = (unsigned int*)(ws + nh * 4);     // 1 u32
    uint32_t* sp2 = (uint32_t*)(ws + nh * 4 + 64);       // packed 2b/atom
    const int n_words = (n_atoms + 15) >> 4;
    const size_t need_table = (size_t)nh * 4 + 64 + (size_t)n_words * 4;
    const bool use_table = ws_size >= need_table;

    hipMemsetAsync(d_ws, 0, nh * 4 + 8, stream);

    k_detect<<<512, 256, 0, stream>>>(oh, n_atoms * NSPEC, nz);

    if (use_table)
        k_species<<<(n_words + 255) / 256, 256, 0, stream>>>(oh, n_atoms, nz,
                                                             sp2);

    const size_t shmem = (size_t)n_edges * 4 + (size_t)nh * 4;
    const int blocks = 2048;
    if (use_table)
        k_hist<true><<<blocks, 256, shmem, stream>>>(
            dist, pf, ps, sp2, oh, nz, n_atoms, bins, n_edges, npairs, counts);
    else
        k_hist<false><<<blocks, 256, shmem, stream>>>(
            dist, pf, ps, sp2, oh, nz, n_atoms, bins, n_edges, npairs, counts);

    k_final<<<(out_size + 255) / 256, 256, 0, stream>>>(counts, nmol, out,
                                                        out_size);
}

// Round 3
// 136.041 us; speedup vs baseline: 1.3233x; 1.1968x over previous
//
#include <hip/hip_runtime.h>
#include <stdint.h>

// ---------------------------------------------------------------------------
// RDFBins: species-pair radial distribution histogram.
//   out[si, sj, b] = #(pairs with species(first)=si, species(second)=sj,
//                      bins[b] <= d < bins[b+1]) / n_molecules
// Inputs (d_in order): pair_dist f32[NP], pair_first i32[NP], pair_second
// i32[NP], one_hot bool[NA,4], n_molecules i32[1], bins f32[NE].
//
// R3: global random gathers were transaction-bound (64 lines per wave-gather).
// Fix: 2-bit species table staged in LDS (random LDS access ~free), 1024-thr
// blocks, 2 blocks/CU, 100% occupancy. Streaming loads are the only global
// traffic in the hot loop.
// ---------------------------------------------------------------------------

#define NSPEC 4
#define TAB_WORDS 16384   // supports up to 262144 atoms (2 bits each)
#define MAX_EDGES 128
#define MAX_NH (NSPEC * NSPEC * (MAX_EDGES - 1))

// Element size of one_hot elements, from count of nonzero 4-byte words in the
// first 4096 bytes (strict one-hot rows):
//   u8 -> 1024 (every word is a row with one nonzero byte)
//   f32/i32 -> 256 (one nonzero word per 16B row)
//   i64/f64 -> 128 (one nonzero word per 32B row)
__device__ inline int esize_from_nzw(unsigned int nzw) {
    if (nzw >= 640) return 1;
    if (nzw >= 192) return 4;
    return 8;
}

__device__ inline int get_species(const uint8_t* oh, int atom, int E) {
    if (E == 1) {
        uint32_t v = *(const uint32_t*)(oh + (size_t)atom * 4);
        if (v & 0x000000FFu) return 0;
        if (v & 0x0000FF00u) return 1;
        if (v & 0x00FF0000u) return 2;
        return 3;
    }
    const uint8_t* p = oh + (size_t)atom * 4 * E;
    for (int s = 0; s < NSPEC; ++s) {
        bool nzb = false;
        for (int b = 0; b < E; ++b) nzb |= (p[s * E + b] != 0);
        if (nzb) return s;
    }
    return 0;
}

// --- kernel 1: one-block probe, count nonzero words in first 4096 B --------
__global__ void k_detect(const uint8_t* __restrict__ oh,
                         unsigned int* __restrict__ nzw_out) {
    __shared__ unsigned int s;
    if (threadIdx.x == 0) s = 0;
    __syncthreads();
    uint32_t v = ((const uint32_t*)oh)[threadIdx.x];  // 1024 threads, 4096 B
    unsigned long long m = __ballot(v != 0u);
    if ((threadIdx.x & 63) == 0) atomicAdd(&s, (unsigned)__popcll(m));
    __syncthreads();
    if (threadIdx.x == 0) *nzw_out = s;
}

// --- kernel 2: species labels packed 2 bits/atom ---------------------------
__global__ void k_species(const uint8_t* __restrict__ oh, int n_atoms,
                          const unsigned int* __restrict__ nzw,
                          uint32_t* __restrict__ sp2) {
    int E = esize_from_nzw(*nzw);
    int tid = blockIdx.x * blockDim.x + threadIdx.x;
    int stride = gridDim.x * blockDim.x;
    int nw = (n_atoms + 15) >> 4;
    for (int w = tid; w < nw; w += stride) {
        uint32_t word = 0;
        int base = w << 4;
        int lim = n_atoms - base;
        lim = lim < 16 ? lim : 16;
        for (int k = 0; k < lim; ++k)
            word |= (uint32_t)get_species(oh, base + k, E) << (k * 2);
        sp2[w] = word;
    }
}

// --- kernel 3 (main): histogram with LDS-resident species table ------------
__launch_bounds__(1024, 8) __global__
void k_hist_lds(const float* __restrict__ dist, const int* __restrict__ pf,
                const int* __restrict__ ps, const uint32_t* __restrict__ sp2,
                const float* __restrict__ bins, int n_edges, int n_words,
                int npairs, unsigned int* __restrict__ counts) {
    __shared__ uint32_t tab[TAB_WORDS];
    __shared__ float sb[MAX_EDGES];
    __shared__ int h[MAX_NH];
    const int n_bins = n_edges - 1;
    const int nh = NSPEC * NSPEC * n_bins;
    const int tid = threadIdx.x;

    for (int j = tid; j < n_words; j += blockDim.x) tab[j] = sp2[j];
    for (int j = tid; j < n_edges; j += blockDim.x) sb[j] = bins[j];
    for (int j = tid; j < nh; j += blockDim.x) h[j] = 0;
    __syncthreads();

    const float lo = sb[0];
    const float hi = sb[n_edges - 1];
    const float scale = (float)n_bins / (hi - lo);

    const int gid = blockIdx.x * blockDim.x + tid;
    const int gsz = gridDim.x * blockDim.x;

    auto species_of = [&](int a) -> int {
        return (int)((tab[a >> 4] >> ((a & 15) << 1)) & 3u);
    };

    auto bin_and_add = [&](float d, int si, int sj) {
        if (d >= lo && d < hi) {
            int b = (int)((d - lo) * scale);
            b = b < n_bins - 1 ? b : n_bins - 1;
            // exact fix-up against real edges (== searchsorted(right)-1)
            while (d < sb[b]) --b;
            while (d >= sb[b + 1]) ++b;
            atomicAdd(&h[(si * NSPEC + sj) * n_bins + b], 1);
        }
    };

    const int nquads = npairs >> 2;
    int q = gid;
    for (; q + gsz < nquads; q += 2 * gsz) {
        const int qa = q, qb = q + gsz;
        float4 dA = ((const float4*)dist)[qa];
        int4 fA = ((const int4*)pf)[qa];
        int4 sA = ((const int4*)ps)[qa];
        float4 dB = ((const float4*)dist)[qb];
        int4 fB = ((const int4*)pf)[qb];
        int4 sB = ((const int4*)ps)[qb];
        bin_and_add(dA.x, species_of(fA.x), species_of(sA.x));
        bin_and_add(dA.y, species_of(fA.y), species_of(sA.y));
        bin_and_add(dA.z, species_of(fA.z), species_of(sA.z));
        bin_and_add(dA.w, species_of(fA.w), species_of(sA.w));
        bin_and_add(dB.x, species_of(fB.x), species_of(sB.x));
        bin_and_add(dB.y, species_of(fB.y), species_of(sB.y));
        bin_and_add(dB.z, species_of(fB.z), species_of(sB.z));
        bin_and_add(dB.w, species_of(fB.w), species_of(sB.w));
    }
    if (q < nquads) {
        float4 d4 = ((const float4*)dist)[q];
        int4 f4 = ((const int4*)pf)[q];
        int4 s4 = ((const int4*)ps)[q];
        bin_and_add(d4.x, species_of(f4.x), species_of(s4.x));
        bin_and_add(d4.y, species_of(f4.y), species_of(s4.y));
        bin_and_add(d4.z, species_of(f4.z), species_of(s4.z));
        bin_and_add(d4.w, species_of(f4.w), species_of(s4.w));
    }
    int tail = npairs & 3;
    if (gid < tail) {
        int i = (nquads << 2) + gid;
        bin_and_add(dist[i], species_of(pf[i]), species_of(ps[i]));
    }

    __syncthreads();
    for (int j = tid; j < nh; j += blockDim.x) {
        int v = h[j];
        if (v) atomicAdd(&counts[j], (unsigned int)v);
    }
}

// --- kernel 3 (fallback): global species table, dynamic LDS ----------------
__launch_bounds__(256, 8) __global__
void k_hist_glb(const float* __restrict__ dist, const int* __restrict__ pf,
                const int* __restrict__ ps, const uint32_t* __restrict__ sp2,
                const float* __restrict__ bins, int n_edges, int npairs,
                unsigned int* __restrict__ counts) {
    const int n_bins = n_edges - 1;
    const int nh = NSPEC * NSPEC * n_bins;
    extern __shared__ float smem[];
    float* sb = smem;
    int* h = (int*)(smem + n_edges);
    const int tid = threadIdx.x;
    for (int j = tid; j < n_edges; j += blockDim.x) sb[j] = bins[j];
    for (int j = tid; j < nh; j += blockDim.x) h[j] = 0;
    __syncthreads();
    const float lo = sb[0];
    const float hi = sb[n_edges - 1];
    const float scale = (float)n_bins / (hi - lo);
    const int gid = blockIdx.x * blockDim.x + tid;
    const int gsz = gridDim.x * blockDim.x;
    auto species_of = [&](int a) -> int {
        return (int)((sp2[a >> 4] >> ((a & 15) << 1)) & 3u);
    };
    auto bin_and_add = [&](float d, int si, int sj) {
        if (d >= lo && d < hi) {
            int b = (int)((d - lo) * scale);
            b = b < n_bins - 1 ? b : n_bins - 1;
            while (d < sb[b]) --b;
            while (d >= sb[b + 1]) ++b;
            atomicAdd(&h[(si * NSPEC + sj) * n_bins + b], 1);
        }
    };
    const int nquads = npairs >> 2;
    for (int q = gid; q < nquads; q += gsz) {
        float4 d4 = ((const float4*)dist)[q];
        int4 f4 = ((const int4*)pf)[q];
        int4 s4 = ((const int4*)ps)[q];
        bin_and_add(d4.x, species_of(f4.x), species_of(s4.x));
        bin_and_add(d4.y, species_of(f4.y), species_of(s4.y));
        bin_and_add(d4.z, species_of(f4.z), species_of(s4.z));
        bin_and_add(d4.w, species_of(f4.w), species_of(s4.w));
    }
    int tail = npairs & 3;
    if (gid < tail) {
        int i = (nquads << 2) + gid;
        bin_and_add(dist[i], species_of(pf[i]), species_of(ps[i]));
    }
    __syncthreads();
    for (int j = tid; j < nh; j += blockDim.x) {
        int v = h[j];
        if (v) atomicAdd(&counts[j], (unsigned int)v);
    }
}

// --- kernel 4: normalize ----------------------------------------------------
__global__ void k_final(const unsigned int* __restrict__ counts,
                        const int* __restrict__ nmol, float* __restrict__ out,
                        int n) {
    int i = blockIdx.x * blockDim.x + threadIdx.x;
    if (i < n) out[i] = (float)counts[i] / (float)(*nmol);
}

extern "C" void kernel_launch(void* const* d_in, const int* in_sizes, int n_in,
                              void* d_out, int out_size, void* d_ws,
                              size_t ws_size, hipStream_t stream) {
    const float* dist = (const float*)d_in[0];
    const int* pf = (const int*)d_in[1];
    const int* ps = (const int*)d_in[2];
    const uint8_t* oh = (const uint8_t*)d_in[3];
    const int* nmol = (const int*)d_in[4];
    const float* bins = (const float*)d_in[5];
    float* out = (float*)d_out;

    const int npairs = in_sizes[0];
    const int n_edges = in_sizes[5];
    const int n_bins = n_edges - 1;
    const int n_atoms = in_sizes[3] / NSPEC;
    const int nh = NSPEC * NSPEC * n_bins;  // 1600 for 101 edges

    uint8_t* ws = (uint8_t*)d_ws;
    unsigned int* counts = (unsigned int*)ws;            // nh u32
    unsigned int* nzw = (unsigned int*)(ws + nh * 4);    // 1 u32
    uint32_t* sp2 = (uint32_t*)(ws + nh * 4 + 64);       // packed 2b/atom
    const int n_words = (n_atoms + 15) >> 4;
    const size_t need = (size_t)nh * 4 + 64 + (size_t)n_words * 4;
    // (workspace is expected to be ample; all paths below need `need` bytes)
    (void)ws_size; (void)need;

    hipMemsetAsync(d_ws, 0, nh * 4 + 8, stream);

    k_detect<<<1, 1024, 0, stream>>>(oh, nzw);
    k_species<<<(n_words + 1023) / 1024, 1024, 0, stream>>>(oh, n_atoms, nzw,
                                                            sp2);

    if (n_words <= TAB_WORDS && n_edges <= MAX_EDGES) {
        k_hist_lds<<<512, 1024, 0, stream>>>(dist, pf, ps, sp2, bins, n_edges,
                                             n_words, npairs, counts);
    } else {
        const size_t shmem = (size_t)n_edges * 4 + (size_t)nh * 4;
        k_hist_glb<<<2048, 256, shmem, stream>>>(dist, pf, ps, sp2, bins,
                                                 n_edges, npairs, counts);
    }

    k_final<<<(out_size + 255) / 256, 256, 0, stream>>>(counts, nmol, out,
                                                        out_size);
}

// Round 4
// 79.713 us; speedup vs baseline: 2.2583x; 1.7066x over previous
//
#include <hip/hip_runtime.h>
#include <stdint.h>

// ---------------------------------------------------------------------------
// RDFBins: species-pair radial distribution histogram.
//   out[si, sj, b] = #(pairs with species(first)=si, species(second)=sj,
//                      bins[b] <= d < bins[b+1]) / n_molecules
// Inputs: pair_dist f32[NP], pair_first i32[NP], pair_second i32[NP],
//         one_hot bool[NA,4], n_molecules i32[1], bins f32[NE].
//
// R4: R3 was dependency-stall-bound (VALUBusy 20%, HBM 17%): the while-loop
// edge fix-up serialized ds_read->cmp->branch chains per pair. Now branchless:
// arithmetic bin guess + one ds_read_b64 of (edge_lo,edge_hi) + +/-1 correct,
// invalid pairs go to LDS dump slots via cndmask. Dispatch count 5 -> 3.
// ---------------------------------------------------------------------------

#define NSPEC 4

// Element size of one_hot elements from count of nonzero 4-byte words in the
// first 4096 bytes (strict one-hot rows):
//   u8 -> 1024 nonzero words; f32/i32 -> 256; i64/f64 -> 128
__device__ inline int esize_from_nzw(unsigned int nzw) {
    if (nzw >= 640) return 1;
    if (nzw >= 192) return 4;
    return 8;
}

__device__ inline int get_species(const uint8_t* oh, int atom, int E) {
    if (E == 1) {
        uint32_t v = *(const uint32_t*)(oh + (size_t)atom * 4);
        if (v & 0x000000FFu) return 0;
        if (v & 0x0000FF00u) return 1;
        if (v & 0x00FF0000u) return 2;
        return 3;
    }
    const uint8_t* p = oh + (size_t)atom * 4 * E;
    for (int s = 0; s < NSPEC; ++s) {
        bool nzb = false;
        for (int b = 0; b < E; ++b) nzb |= (p[s * E + b] != 0);
        if (nzb) return s;
    }
    return 0;
}

// --- kernel 1: detect elem width, zero counts, pack species 2 bits/atom ----
__global__ void k_species(const uint8_t* __restrict__ oh, int n_atoms,
                          uint32_t* __restrict__ sp2,
                          unsigned int* __restrict__ counts, int n_counts) {
    __shared__ unsigned int s_nz;
    if (threadIdx.x == 0) s_nz = 0;
    __syncthreads();
    unsigned int local = 0;
    #pragma unroll
    for (int k = 0; k < 4; ++k) {  // 256 threads x 4 words = first 4096 B
        uint32_t v = ((const uint32_t*)oh)[threadIdx.x * 4 + k];
        local += (v != 0u);
    }
    for (int off = 32; off > 0; off >>= 1) local += __shfl_down(local, off);
    if ((threadIdx.x & 63) == 0) atomicAdd(&s_nz, local);
    __syncthreads();
    const int E = esize_from_nzw(s_nz);

    const int gid = blockIdx.x * blockDim.x + threadIdx.x;
    const int gsz = gridDim.x * blockDim.x;
    for (int j = gid; j < n_counts; j += gsz) counts[j] = 0u;

    const int nw = (n_atoms + 15) >> 4;
    for (int w = gid; w < nw; w += gsz) {
        uint32_t word = 0;
        int base = w << 4;
        int lim = n_atoms - base;
        lim = lim < 16 ? lim : 16;
        for (int k = 0; k < lim; ++k)
            word |= (uint32_t)get_species(oh, base + k, E) << (k * 2);
        sp2[w] = word;
    }
}

// --- kernel 2 (main): branchless histogram, LDS species table --------------
// dyn LDS layout: float2 eb[n_bins] | uint32 tab[n_words] | int h[nh+8]
__launch_bounds__(1024, 8) __global__
void k_hist_lds(const float* __restrict__ dist, const int* __restrict__ pf,
                const int* __restrict__ ps, const uint32_t* __restrict__ sp2,
                const float* __restrict__ bins, int n_edges, int n_words,
                int npairs, unsigned int* __restrict__ counts) {
    extern __shared__ float2 smem2[];
    const int n_bins = n_edges - 1;
    const int nh = NSPEC * NSPEC * n_bins;
    float2* eb = smem2;
    uint32_t* tab = (uint32_t*)(eb + n_bins);
    int* h = (int*)(tab + n_words);
    __shared__ int s_uniform;

    const int tid = threadIdx.x;
    if (tid == 0) s_uniform = 1;
    __syncthreads();

    for (int j = tid; j < n_words; j += blockDim.x) tab[j] = sp2[j];
    for (int j = tid; j < nh + 8; j += blockDim.x) h[j] = 0;
    const float lo = bins[0];
    const float hi = bins[n_edges - 1];
    const float w = (hi - lo) / (float)n_bins;
    for (int j = tid; j < n_bins; j += blockDim.x) {
        float2 e = make_float2(bins[j], bins[j + 1]);
        eb[j] = e;
        // near-uniform check: each edge within w/4 of ideal uniform position
        float id0 = lo + (float)j * w;
        float id1 = lo + (float)(j + 1) * w;
        if (fabsf(e.x - id0) > 0.25f * w || fabsf(e.y - id1) > 0.25f * w)
            atomicAnd(&s_uniform, 0);
    }
    __syncthreads();

    const float scale = (float)n_bins / (hi - lo);
    const int gid = blockIdx.x * blockDim.x + tid;
    const int gsz = gridDim.x * blockDim.x;
    const int nquads = npairs >> 2;
    const int dump = nh + (tid & 7);

    if (s_uniform) {
        for (int q = gid; q < nquads; q += gsz) {
            float4 d4 = ((const float4*)dist)[q];
            int4 f4 = ((const int4*)pf)[q];
            int4 s4 = ((const int4*)ps)[q];
            float d[4] = {d4.x, d4.y, d4.z, d4.w};
            int a0[4] = {f4.x, f4.y, f4.z, f4.w};
            int a1[4] = {s4.x, s4.y, s4.z, s4.w};
            int g[4], vld[4];
            #pragma unroll
            for (int k = 0; k < 4; ++k) {
                int gi = (int)((d[k] - lo) * scale);
                gi = gi < n_bins - 1 ? gi : n_bins - 1;
                g[k] = gi > 0 ? gi : 0;
                vld[k] = (d[k] >= lo) & (d[k] < hi);
            }
            float2 e[4];
            uint32_t wi[4], wj[4];
            #pragma unroll
            for (int k = 0; k < 4; ++k) e[k] = eb[g[k]];
            #pragma unroll
            for (int k = 0; k < 4; ++k) {
                wi[k] = tab[(unsigned)a0[k] >> 4];
                wj[k] = tab[(unsigned)a1[k] >> 4];
            }
            #pragma unroll
            for (int k = 0; k < 4; ++k) {
                // exact ±1 correction vs true edges (== searchsorted(right)-1)
                int b = g[k] - (d[k] < e[k].x) + (d[k] >= e[k].y);
                int si = (int)((wi[k] >> ((a0[k] & 15) << 1)) & 3u);
                int sj = (int)((wj[k] >> ((a1[k] & 15) << 1)) & 3u);
                int idx = (si * NSPEC + sj) * n_bins + b;
                atomicAdd(&h[vld[k] ? idx : dump], 1);
            }
        }
    } else {
        // safe path for non-uniform bins: while-loop fix-up
        for (int q = gid; q < nquads; q += gsz) {
            float4 d4 = ((const float4*)dist)[q];
            int4 f4 = ((const int4*)pf)[q];
            int4 s4 = ((const int4*)ps)[q];
            float d[4] = {d4.x, d4.y, d4.z, d4.w};
            int a0[4] = {f4.x, f4.y, f4.z, f4.w};
            int a1[4] = {s4.x, s4.y, s4.z, s4.w};
            #pragma unroll
            for (int k = 0; k < 4; ++k) {
                if (d[k] >= lo && d[k] < hi) {
                    int b = (int)((d[k] - lo) * scale);
                    b = b < n_bins - 1 ? b : n_bins - 1;
                    b = b > 0 ? b : 0;
                    while (d[k] < eb[b].x) --b;
                    while (d[k] >= eb[b].y) ++b;
                    int si = get_species((const uint8_t*)0, 0, 0);  // unused
                    (void)si;
                    int s_i = (int)((tab[(unsigned)a0[k] >> 4] >>
                                     ((a0[k] & 15) << 1)) & 3u);
                    int s_j = (int)((tab[(unsigned)a1[k] >> 4] >>
                                     ((a1[k] & 15) << 1)) & 3u);
                    atomicAdd(&h[(s_i * NSPEC + s_j) * n_bins + b], 1);
                }
            }
        }
    }
    // tail (npairs % 4) — always safe path
    int tail = npairs & 3;
    if (gid < tail) {
        int i = (nquads << 2) + gid;
        float d = dist[i];
        if (d >= lo && d < hi) {
            int b = (int)((d - lo) * scale);
            b = b < n_bins - 1 ? b : n_bins - 1;
            b = b > 0 ? b : 0;
            while (d < eb[b].x) --b;
            while (d >= eb[b].y) ++b;
            int a0 = pf[i], a1 = ps[i];
            int s_i = (int)((tab[(unsigned)a0 >> 4] >> ((a0 & 15) << 1)) & 3u);
            int s_j = (int)((tab[(unsigned)a1 >> 4] >> ((a1 & 15) << 1)) & 3u);
            atomicAdd(&h[(s_i * NSPEC + s_j) * n_bins + b], 1);
        }
    }

    __syncthreads();
    for (int j = tid; j < nh; j += blockDim.x) {
        int v = h[j];
        if (v) atomicAdd(&counts[j], (unsigned int)v);
    }
}

// --- kernel 2 (fallback): global species table, for oversized inputs -------
__launch_bounds__(256, 8) __global__
void k_hist_glb(const float* __restrict__ dist, const int* __restrict__ pf,
                const int* __restrict__ ps, const uint32_t* __restrict__ sp2,
                const float* __restrict__ bins, int n_edges, int npairs,
                unsigned int* __restrict__ counts) {
    const int n_bins = n_edges - 1;
    const int nh = NSPEC * NSPEC * n_bins;
    extern __shared__ float smem[];
    float* sb = smem;
    int* h = (int*)(smem + n_edges);
    const int tid = threadIdx.x;
    for (int j = tid; j < n_edges; j += blockDim.x) sb[j] = bins[j];
    for (int j = tid; j < nh; j += blockDim.x) h[j] = 0;
    __syncthreads();
    const float lo = sb[0];
    const float hi = sb[n_edges - 1];
    const float scale = (float)n_bins / (hi - lo);
    const int gid = blockIdx.x * blockDim.x + tid;
    const int gsz = gridDim.x * blockDim.x;
    auto species_of = [&](int a) -> int {
        return (int)((sp2[a >> 4] >> ((a & 15) << 1)) & 3u);
    };
    auto bin_and_add = [&](float d, int si, int sj) {
        if (d >= lo && d < hi) {
            int b = (int)((d - lo) * scale);
            b = b < n_bins - 1 ? b : n_bins - 1;
            b = b > 0 ? b : 0;
            while (d < sb[b]) --b;
            while (d >= sb[b + 1]) ++b;
            atomicAdd(&h[(si * NSPEC + sj) * n_bins + b], 1);
        }
    };
    const int nquads = npairs >> 2;
    for (int q = gid; q < nquads; q += gsz) {
        float4 d4 = ((const float4*)dist)[q];
        int4 f4 = ((const int4*)pf)[q];
        int4 s4 = ((const int4*)ps)[q];
        bin_and_add(d4.x, species_of(f4.x), species_of(s4.x));
        bin_and_add(d4.y, species_of(f4.y), species_of(s4.y));
        bin_and_add(d4.z, species_of(f4.z), species_of(s4.z));
        bin_and_add(d4.w, species_of(f4.w), species_of(s4.w));
    }
    int tail = npairs & 3;
    if (gid < tail) {
        int i = (nquads << 2) + gid;
        bin_and_add(dist[i], species_of(pf[i]), species_of(ps[i]));
    }
    __syncthreads();
    for (int j = tid; j < nh; j += blockDim.x) {
        int v = h[j];
        if (v) atomicAdd(&counts[j], (unsigned int)v);
    }
}

// --- kernel 3: normalize ----------------------------------------------------
__global__ void k_final(const unsigned int* __restrict__ counts,
                        const int* __restrict__ nmol, float* __restrict__ out,
                        int n) {
    int i = blockIdx.x * blockDim.x + threadIdx.x;
    if (i < n) out[i] = (float)counts[i] / (float)(*nmol);
}

extern "C" void kernel_launch(void* const* d_in, const int* in_sizes, int n_in,
                              void* d_out, int out_size, void* d_ws,
                              size_t ws_size, hipStream_t stream) {
    const float* dist = (const float*)d_in[0];
    const int* pf = (const int*)d_in[1];
    const int* ps = (const int*)d_in[2];
    const uint8_t* oh = (const uint8_t*)d_in[3];
    const int* nmol = (const int*)d_in[4];
    const float* bins = (const float*)d_in[5];
    float* out = (float*)d_out;

    const int npairs = in_sizes[0];
    const int n_edges = in_sizes[5];
    const int n_bins = n_edges - 1;
    const int n_atoms = in_sizes[3] / NSPEC;
    const int nh = NSPEC * NSPEC * n_bins;  // 1600 for 101 edges

    uint8_t* ws = (uint8_t*)d_ws;
    unsigned int* counts = (unsigned int*)ws;         // nh u32
    uint32_t* sp2 = (uint32_t*)(ws + nh * 4 + 64);    // packed 2b/atom
    const int n_words = (n_atoms + 15) >> 4;

    k_species<<<256, 256, 0, stream>>>(oh, n_atoms, sp2, counts, nh);

    const size_t shmem_lds = (size_t)n_bins * 8 + (size_t)n_words * 4 +
                             (size_t)(nh + 8) * 4;
    if (shmem_lds <= 64 * 1024) {
        k_hist_lds<<<512, 1024, shmem_lds, stream>>>(
            dist, pf, ps, sp2, bins, n_edges, n_words, npairs, counts);
    } else {
        const size_t shmem = (size_t)n_edges * 4 + (size_t)nh * 4;
        k_hist_glb<<<2048, 256, shmem, stream>>>(dist, pf, ps, sp2, bins,
                                                 n_edges, npairs, counts);
    }

    k_final<<<(out_size + 255) / 256, 256, 0, stream>>>(counts, nmol, out,
                                                        out_size);
}